// Round 16
// baseline (929.613 us; speedup 1.0000x reference)
//
#include <hip/hip_runtime.h>
#include <hip/hip_bf16.h>

#define N_NODES 50176
#define PER 392
#define E_BI (N_NODES * 4)      // 200704
#define E_KNN (N_NODES * 16)    // 802816
#define E_TOT (E_BI + E_KNN)    // 1003520
#define KN_BI (N_NODES * 5)     // 250880
#define KN_TOT (N_NODES * 14)   // 702464
#define AH_S 416                // ah row stride (shorts): [a(128)|h(128)|cnt(32)|feat(128)]
#define AH_U 208                // ... in uints

typedef __attribute__((ext_vector_type(8))) short short8;
typedef __attribute__((ext_vector_type(4))) float float4v;
typedef unsigned int uint;
typedef unsigned short ushort;

__device__ __forceinline__ float sigmoidf_(float x) { return 1.f / (1.f + __expf(-x)); }
__device__ __forceinline__ ushort f2bu(float x) {
    __hip_bfloat16 t = __float2bfloat16(x);
    return *reinterpret_cast<ushort*>(&t);
}
__device__ __forceinline__ float blo(uint u) { return __uint_as_float(u << 16); }
__device__ __forceinline__ float bhi(uint u) { return __uint_as_float(u & 0xFFFF0000u); }

// direct global->LDS DMA, 16B per lane; LDS dest = wave-uniform base + lane*16
__device__ __forceinline__ void gld_lds16(const ushort* g, ushort* l)
{
    __builtin_amdgcn_global_load_lds(
        (const __attribute__((address_space(1))) void*)g,
        (__attribute__((address_space(3))) void*)l, 16, 0, 0);
}

// ================= fused aggregate + per-etype transform (v4 — measured optimum) ======
// Block = 32 node rows, 256 threads: 8 threads/row (16 ch each, 2x16B loads/edge).
// NOTE: r8 (thread reshape), r11 (parity split), r12 (pairwise unroll) all regressed
// vs this exact loop body — do not reshape the gather.
template<int NET>
__global__ __launch_bounds__(256) void msg_kernel(
    const uint* __restrict__ hb,           // [N][64] uints (h bf16 packed)
    const int* __restrict__ indptr,        // [N*NET+1] slice (absolute into elist)
    const int* __restrict__ elist,
    const ushort* __restrict__ Bfrag,      // fragment-ordered weights
    ushort* __restrict__ aout)             // target ah buffer; write cols 0..127
{
    __shared__ ushort As[4][32][40];       // 10.25 KB, chunk-major, 80B rows
    const int tid = threadIdx.x;
    const int bm = blockIdx.x * 32;
    const int wave = tid >> 6, lane = tid & 63;
    const int quad = lane >> 4, lrow = lane & 15;
    const int wr = wave & 1, wc = wave >> 1;
    const int r = tid >> 3;                // node row 0..31
    const int oct = tid & 7;               // 16-ch group
    const int v = bm + r;

    uint* AsU = (uint*)As;                 // [ch][r][20] uints

    float4v acc[4] = {};

    for (int et = 0; et < NET; et++) {
        const int beg = indptr[v * NET + et], end = indptr[v * NET + et + 1];
        float av[16];
#pragma unroll
        for (int i = 0; i < 16; i++) av[i] = 0.f;

        for (int j = beg; j < end; j++) {
            int src = elist[j];
            const uint4* hp = (const uint4*)(hb + (size_t)src * 64 + oct * 8);
            uint4 u0 = hp[0];
            uint4 u1 = hp[1];
            av[0] += blo(u0.x); av[1] += bhi(u0.x);
            av[2] += blo(u0.y); av[3] += bhi(u0.y);
            av[4] += blo(u0.z); av[5] += bhi(u0.z);
            av[6] += blo(u0.w); av[7] += bhi(u0.w);
            av[8]  += blo(u1.x); av[9]  += bhi(u1.x);
            av[10] += blo(u1.y); av[11] += bhi(u1.y);
            av[12] += blo(u1.z); av[13] += bhi(u1.z);
            av[14] += blo(u1.w); av[15] += bhi(u1.w);
        }

        __syncthreads();                   // previous etype's As reads complete
        {
            int base = ((oct >> 1) * 32 + r) * 20 + (oct & 1) * 8;
#pragma unroll
            for (int u = 0; u < 8; u++)
                AsU[base + u] = (uint)f2bu(av[2 * u]) | ((uint)f2bu(av[2 * u + 1]) << 16);
        }
        __syncthreads();

#pragma unroll
        for (int ch = 0; ch < 4; ch++) {
            short8 af = *(const short8*)&As[ch][wr * 16 + lrow][quad * 8];
            const ushort* bp = Bfrag + ((size_t)(((et * 4 + ch) * 2 + wc) * 4) << 9) + lane * 8;
#pragma unroll
            for (int j2 = 0; j2 < 4; j2++) {
                short8 bfr = *(const short8*)(bp + j2 * 512);
                acc[j2] = __builtin_amdgcn_mfma_f32_16x16x32_bf16(af, bfr, acc[j2], 0, 0, 0);
            }
        }
    }

#pragma unroll
    for (int j2 = 0; j2 < 4; j2++) {
        int col = wc * 64 + j2 * 16 + lrow;
#pragma unroll
        for (int rr = 0; rr < 4; rr++) {
            size_t row = (size_t)(bm + wr * 16 + quad * 4 + rr);
            aout[row * AH_S + col] = f2bu(acc[j2][rr]);
        }
    }
}

// ================= GRU GEMM with fused gate epilogue (ping-pong, race-free) ============
__global__ __launch_bounds__(256) void gru_gemm_kernel(
    const ushort* __restrict__ A,          // ahIn base, lda AH_S
    const ushort* __restrict__ Bt,         // gruB [512][288] permuted
    const float* __restrict__ bias,        // [512] permuted
    ushort* __restrict__ ahOut, ushort* __restrict__ hbS)
{
    __shared__ ushort As[128 * 32];
    __shared__ ushort Bs[128 * 32];
    const int tid = threadIdx.x;
    const int bm = blockIdx.x * 128;
    const int bn = blockIdx.y * 128;
    const int wave = tid >> 6, lane = tid & 63;
    const int quad = lane >> 4, lrow = lane & 15;
    const int wr = wave & 1, wc = wave >> 1;

    float4v acc[4][4] = {};

    for (int k0 = 0; k0 < 288; k0 += 32) {
        __syncthreads();
#pragma unroll
        for (int p = 0; p < 2; p++) {
            int lin = p * 256 + tid;
            int r = lin >> 2;
            int kc = (lin & 3) * 8;
            int wb = (p * 256 + wave * 64) * 8;       // wave-uniform LDS base (ushorts)
            gld_lds16(A + (size_t)(bm + r) * AH_S + k0 + kc, &As[wb]);
            gld_lds16(Bt + (size_t)(bn + r) * 288 + k0 + kc, &Bs[wb]);
        }
        __syncthreads();
        short8 af[4], bfr[4];
#pragma unroll
        for (int i = 0; i < 4; i++)
            af[i] = *(const short8*)&As[(wr * 64 + i * 16 + lrow) * 32 + quad * 8];
#pragma unroll
        for (int j = 0; j < 4; j++)
            bfr[j] = *(const short8*)&Bs[(wc * 64 + j * 16 + lrow) * 32 + quad * 8];
#pragma unroll
        for (int i = 0; i < 4; i++)
#pragma unroll
            for (int j = 0; j < 4; j++)
                acc[i][j] = __builtin_amdgcn_mfma_f32_16x16x32_bf16(af[i], bfr[j], acc[i][j], 0, 0, 0);
    }

    const int ch = (bn >> 7) * 32 + wc * 16 + lrow;
    const float b0 = bias[bn + wc * 64 + lrow];
    const float b1 = bias[bn + wc * 64 + 16 + lrow];
    const float b2 = bias[bn + wc * 64 + 32 + lrow];
    const float b3 = bias[bn + wc * 64 + 48 + lrow];
#pragma unroll
    for (int i = 0; i < 4; i++) {
#pragma unroll
        for (int r = 0; r < 4; r++) {
            size_t row = (size_t)(bm + wr * 64 + i * 16 + quad * 4 + r);
            float rr = sigmoidf_(acc[i][0][r] + b0);
            float zz = sigmoidf_(acc[i][1][r] + b1);
            float nn = tanhf(acc[i][2][r] + b2 + rr * (acc[i][3][r] + b3));
            float hold = __uint_as_float(((uint)A[row * AH_S + 128 + ch]) << 16);
            float hnew = (1.f - zz) * nn + zz * hold;
            ushort hu = f2bu(hnew);
            ahOut[row * AH_S + 128 + ch] = hu;
            hbS[row * 128 + ch] = hu;
        }
    }
}

// ================= readout GEMM with fused sigmoid-mul epilogue =================
// Stage-1 mode (ahx != null): write o into ahx (the OTHER ping-pong buffer — never
// read by this kernel, so race-free): h-cols + feat-cols, plus hb. Stage 2 then
// starts with ahIn = ahx.
// Stage-2 mode (rb != null): write bf16 rout only.
__global__ __launch_bounds__(256) void ro_gemm_kernel(
    const ushort* __restrict__ A,
    const ushort* __restrict__ Bt,         // [256][288]
    const float* __restrict__ bias,        // [256] permuted
    ushort* __restrict__ rb,
    ushort* __restrict__ ahx, ushort* __restrict__ hbS)
{
    __shared__ ushort As[128 * 32];
    __shared__ ushort Bs[128 * 32];
    const int tid = threadIdx.x;
    const int bm = blockIdx.x * 128;
    const int bn = blockIdx.y * 128;
    const int wave = tid >> 6, lane = tid & 63;
    const int quad = lane >> 4, lrow = lane & 15;
    const int wr = wave & 1, wc = wave >> 1;

    float4v acc[4][4] = {};

    for (int k0 = 0; k0 < 288; k0 += 32) {
        __syncthreads();
#pragma unroll
        for (int p = 0; p < 2; p++) {
            int lin = p * 256 + tid;
            int r = lin >> 2;
            int kc = (lin & 3) * 8;
            int wb = (p * 256 + wave * 64) * 8;
            gld_lds16(A + (size_t)(bm + r) * AH_S + k0 + kc, &As[wb]);
            gld_lds16(Bt + (size_t)(bn + r) * 288 + k0 + kc, &Bs[wb]);
        }
        __syncthreads();
        short8 af[4], bfr[4];
#pragma unroll
        for (int i = 0; i < 4; i++)
            af[i] = *(const short8*)&As[(wr * 64 + i * 16 + lrow) * 32 + quad * 8];
#pragma unroll
        for (int j = 0; j < 4; j++)
            bfr[j] = *(const short8*)&Bs[(wc * 64 + j * 16 + lrow) * 32 + quad * 8];
#pragma unroll
        for (int i = 0; i < 4; i++)
#pragma unroll
            for (int j = 0; j < 4; j++)
                acc[i][j] = __builtin_amdgcn_mfma_f32_16x16x32_bf16(af[i], bfr[j], acc[i][j], 0, 0, 0);
    }

    const int c0 = (bn >> 7) * 64 + wc * 32 + lrow;
    const int c1 = c0 + 16;
    const float bu0 = bias[bn + wc * 64 + lrow];
    const float bv0 = bias[bn + wc * 64 + 16 + lrow];
    const float bu1 = bias[bn + wc * 64 + 32 + lrow];
    const float bv1 = bias[bn + wc * 64 + 48 + lrow];
#pragma unroll
    for (int i = 0; i < 4; i++) {
#pragma unroll
        for (int r = 0; r < 4; r++) {
            size_t row = (size_t)(bm + wr * 64 + i * 16 + quad * 4 + r);
            float o0 = sigmoidf_(acc[i][0][r] + bu0) * (acc[i][1][r] + bv0);
            float o1 = sigmoidf_(acc[i][2][r] + bu1) * (acc[i][3][r] + bv1);
            ushort u0 = f2bu(o0), u1 = f2bu(o1);
            if (rb) {
                rb[row * 128 + c0] = u0;
                rb[row * 128 + c1] = u1;
            }
            if (ahx) {
                ahx[row * AH_S + 128 + c0] = u0;   // stage-2 h init
                ahx[row * AH_S + 128 + c1] = u1;
                ahx[row * AH_S + 288 + c0] = u0;   // stage-2 feat cols (read only at ro)
                ahx[row * AH_S + 288 + c1] = u1;
                hbS[row * 128 + c0] = u0;
                hbS[row * 128 + c1] = u1;
            }
        }
    }
}

// ================= small fp32 GEMM (stage-3 x1 only) =================
__global__ __launch_bounds__(256) void gemm_kernel(
    const float* __restrict__ A, int lda,
    const float* __restrict__ B, int ldb,
    const float* __restrict__ bias,
    float* __restrict__ C, int ldc,
    int K, int act)
{
    __shared__ float As[32][68];
    __shared__ float Bs[32][68];
    const int tid = threadIdx.x;
    const int bm = blockIdx.x * 64;
    const int bn = blockIdx.y * 64;
    const int tm = (tid & 15) * 4;
    const int tn = (tid >> 4) * 4;
    float acc[4][4] = {};

    for (int k0 = 0; k0 < K; k0 += 32) {
#pragma unroll
        for (int p = 0; p < 2; p++) {
            int lin = p * 256 + tid;
            int ar = lin >> 3;
            int ac = (lin & 7) << 2;
            float4 av = *(const float4*)(A + (size_t)(bm + ar) * lda + (k0 + ac));
            As[ac + 0][ar] = av.x;
            As[ac + 1][ar] = av.y;
            As[ac + 2][ar] = av.z;
            As[ac + 3][ar] = av.w;
            int br = lin >> 4;
            int bc = (lin & 15) << 2;
            *(float4*)&Bs[br][bc] = *(const float4*)(B + (size_t)(k0 + br) * ldb + (bn + bc));
        }
        __syncthreads();
#pragma unroll
        for (int k = 0; k < 32; k++) {
            float4 a4 = *(const float4*)&As[k][tm];
            float4 b4 = *(const float4*)&Bs[k][tn];
            float av[4] = {a4.x, a4.y, a4.z, a4.w};
            float bv[4] = {b4.x, b4.y, b4.z, b4.w};
#pragma unroll
            for (int i = 0; i < 4; i++)
#pragma unroll
                for (int j = 0; j < 4; j++)
                    acc[i][j] += av[i] * bv[j];
        }
        __syncthreads();
    }
#pragma unroll
    for (int i = 0; i < 4; i++) {
        size_t row = (size_t)(bm + tm + i);
#pragma unroll
        for (int j = 0; j < 4; j++) {
            int col = bn + tn + j;
            float val = acc[i][j] + (bias ? bias[col] : 0.f);
            if (act == 1) val = fmaxf(val, 0.f);
            C[row * ldc + col] = val;
        }
    }
}

// ================= fused x2 + output dot (stage 3) =================
__global__ __launch_bounds__(256) void mlp2_kernel(
    const float* __restrict__ x1, const float* __restrict__ w1,
    const float* __restrict__ b1, const float* __restrict__ wo,
    const float* __restrict__ bo, float* __restrict__ out)
{
    __shared__ float part[256];
    int t = threadIdx.x;
    int row = t >> 2;
    int pq = t & 3;
    float acc[32];
#pragma unroll
    for (int i = 0; i < 32; i++) acc[i] = 0.f;
    const float* xr = x1 + row * 256;
    for (int k = 0; k < 256; k++) {
        float xv = xr[k];
        const float* wr = w1 + k * 128 + pq * 32;
#pragma unroll
        for (int i = 0; i < 32; i++) acc[i] += xv * wr[i];
    }
    float s = 0.f;
#pragma unroll
    for (int i = 0; i < 32; i++) {
        float v = fmaxf(acc[i] + b1[pq * 32 + i], 0.f);
        s += v * wo[pq * 32 + i];
    }
    part[t] = s;
    __syncthreads();
    if (pq == 0) out[row] = part[t] + part[t + 1] + part[t + 2] + part[t + 3] + bo[0];
}

// ================= fused weight prep (both stages, one dispatch) =================
__device__ __forceinline__ void prep_bfrag_item(const float* W, ushort* Bf, int idx)
{
    int m = idx & 7;
    int lane = (idx >> 3) & 63;
    int f = idx >> 9;
    int j = f & 3; f >>= 2;
    int wc = f & 1; f >>= 1;
    int ch = f & 3;
    int et = f >> 2;
    int quad = lane >> 4, lrow = lane & 15;
    int k = ch * 32 + quad * 8 + m;
    int c = wc * 64 + j * 16 + lrow;
    Bf[idx] = f2bu(W[et * 16384 + k * 128 + c]);
}

__device__ __forceinline__ void prep_gru_item(const float* wih, const float* whh,
                                              const float* bih, const float* bhh,
                                              const float* b, int net,
                                              ushort* Bt, float* bias, int idx)
{
    int p = idx / 288;
    int k = idx - p * 288;
    int g = (p >> 4) & 3;
    int c = (p >> 7) * 32 + ((p >> 6) & 1) * 16 + (p & 15);
    float val = 0.f;
    if (k < 128) {
        if (g == 0)      val = wih[k * 384 + c];
        else if (g == 1) val = wih[k * 384 + 128 + c];
        else if (g == 2) val = wih[k * 384 + 256 + c];
    } else if (k < 256) {
        int kk = k - 128;
        if (g == 0)      val = whh[kk * 384 + c];
        else if (g == 1) val = whh[kk * 384 + 128 + c];
        else if (g == 3) val = whh[kk * 384 + 256 + c];
    } else {
        int j = k - 256;
        if (j < net && g < 3) {
            int col = g * 128 + c;
            float s = 0.f;
            for (int kk = 0; kk < 128; kk++) s += b[j * 128 + kk] * wih[kk * 384 + col];
            val = s;
        }
    }
    Bt[idx] = f2bu(val);
    if (k == 0) {
        float bv;
        if (g == 0)      bv = bih[c] + bhh[c];
        else if (g == 1) bv = bih[128 + c] + bhh[128 + c];
        else if (g == 2) bv = bih[256 + c];
        else             bv = bhh[256 + c];
        bias[p] = bv;
    }
}

__device__ __forceinline__ void prep_ro_item(const float* iw, const float* jw,
                                             const float* ib, const float* jb,
                                             int Fin, ushort* Bt, float* bias, int idx)
{
    int p = idx / 288;
    int k = idx - p * 288;
    int j = (p >> 4) & 3;
    int s = j & 1;
    int c = ((p >> 7) & 1) * 64 + ((p >> 6) & 1) * 32 + (j >> 1) * 16 + (p & 15);
    float val = 0.f;
    if (k < 128) {
        val = s ? jw[k * 128 + c] : iw[k * 128 + c];
    } else if (k >= 160) {
        int kf = k - 160;
        if (kf < Fin && s == 0) val = iw[(128 + kf) * 128 + c];
    }
    Bt[idx] = f2bu(val);
    if (k == 0) bias[p] = s ? jb[c] : ib[c];
}

// sections: bf1 81920 | gru1 147456 | ro1 73728 | bf2 147456 | gru2 147456 | ro2 73728
__global__ __launch_bounds__(256) void prep_all_kernel(
    const float* W1, const float* b1, const float* wih1, const float* whh1,
    const float* bih1, const float* bhh1, const float* iw1, const float* ib1,
    const float* jw1, const float* jb1,
    const float* W2, const float* b2, const float* wih2, const float* whh2,
    const float* bih2, const float* bhh2, const float* iw2, const float* ib2,
    const float* jw2, const float* jb2,
    ushort* bf1, ushort* gru1, float* gb1, ushort* ro1, float* rb1,
    ushort* bf2, ushort* gru2, float* gb2, ushort* ro2, float* rb2)
{
    int gid = blockIdx.x * 256 + threadIdx.x;
    if (gid < 81920)            prep_bfrag_item(W1, bf1, gid);
    else if (gid < 229376)      prep_gru_item(wih1, whh1, bih1, bhh1, b1, 5, gru1, gb1, gid - 81920);
    else if (gid < 303104)      prep_ro_item(iw1, jw1, ib1, jb1, 64, ro1, rb1, gid - 229376);
    else if (gid < 450560)      prep_bfrag_item(W2, bf2, gid - 303104);
    else if (gid < 598016)      prep_gru_item(wih2, whh2, bih2, bhh2, b2, 9, gru2, gb2, gid - 450560);
    else                        prep_ro_item(iw2, jw2, ib2, jb2, 128, ro2, rb2, gid - 598016);
}

// ================= merged CSR build =================
__global__ void hist2_kernel(const int* __restrict__ bd, const int* __restrict__ be,
                             const int* __restrict__ kd, const int* __restrict__ ke,
                             int* __restrict__ counts)
{
    int e = blockIdx.x * blockDim.x + threadIdx.x;
    if (e >= E_TOT) return;
    if (e < E_BI) atomicAdd(&counts[bd[e] * 5 + be[e]], 1);
    else { int i = e - E_BI; atomicAdd(&counts[KN_BI + kd[i] * 9 + ke[i]], 1); }
}

__global__ void scan1_kernel(const int* __restrict__ counts, int* __restrict__ local_ex,
                             int* __restrict__ partial)
{
    __shared__ int s[256];
    int t = threadIdx.x;
    int i = blockIdx.x * 256 + t;
    int v = counts[i];
    s[t] = v;
    __syncthreads();
    for (int off = 1; off < 256; off <<= 1) {
        int x = 0;
        if (t >= off) x = s[t - off];
        __syncthreads();
        if (t >= off) s[t] += x;
        __syncthreads();
    }
    local_ex[i] = s[t] - v;
    if (t == 255) partial[blockIdx.x] = s[255];
}

__global__ void scan2b_kernel(int* __restrict__ partial, int nb, int* __restrict__ last, int E)
{
    __shared__ int s[256];
    int t = threadIdx.x;
    int loc[11];
    int sum = 0;
#pragma unroll
    for (int q = 0; q < 11; q++) {
        int idx = t * 11 + q;
        int v = (idx < nb) ? partial[idx] : 0;
        loc[q] = sum; sum += v;
    }
    s[t] = sum;
    __syncthreads();
    for (int off = 1; off < 256; off <<= 1) {
        int x = 0;
        if (t >= off) x = s[t - off];
        __syncthreads();
        if (t >= off) s[t] += x;
        __syncthreads();
    }
    int excl = s[t] - sum;
#pragma unroll
    for (int q = 0; q < 11; q++) {
        int idx = t * 11 + q;
        if (idx < nb) partial[idx] = excl + loc[q];
    }
    if (t == 0) *last = E;
}

__global__ void scan3c_kernel(int* __restrict__ indptr, const int* __restrict__ partial,
                              int* __restrict__ cursor)
{
    int i = blockIdx.x * 256 + threadIdx.x;
    int v = indptr[i] + partial[blockIdx.x];
    indptr[i] = v;
    cursor[i] = v;
}

__global__ void fill2_kernel(const int* __restrict__ bs, const int* __restrict__ bd,
                             const int* __restrict__ be,
                             const int* __restrict__ ks, const int* __restrict__ kd,
                             const int* __restrict__ ke,
                             int* __restrict__ cursor, int* __restrict__ elist)
{
    int e = blockIdx.x * blockDim.x + threadIdx.x;
    if (e >= E_TOT) return;
    if (e < E_BI) {
        int pos = atomicAdd(&cursor[bd[e] * 5 + be[e]], 1);
        elist[pos] = bs[e];
    } else {
        int i = e - E_BI;
        int pos = atomicAdd(&cursor[KN_BI + kd[i] * 9 + ke[i]], 1);
        elist[pos] = ks[i];
    }
}

// ================= elementwise =================
// stage-1 pad: feat fp32 -> ahA h-cols + feat cols (both) + hb + cnt cols (both)
__global__ void pad_cnt_kernel(const float* __restrict__ fsrc,
                               const int* __restrict__ indptr, int net,
                               uint* __restrict__ ahA, uint* __restrict__ ahB,
                               uint* __restrict__ hb, int Fin)
{
    int idx = blockIdx.x * blockDim.x + threadIdx.x;   // N*32
    int v = idx >> 5;
    int j = idx & 31;
    int c = j * 4;
    float4 val = make_float4(0.f, 0.f, 0.f, 0.f);
    if (c < Fin) val = *(const float4*)(fsrc + (size_t)v * Fin + c);
    uint2 pk;
    pk.x = (uint)f2bu(val.x) | ((uint)f2bu(val.y) << 16);
    pk.y = (uint)f2bu(val.z) | ((uint)f2bu(val.w) << 16);
    *(uint2*)(ahA + (size_t)v * AH_U + 64 + c / 2) = pk;    // h cols (step-0 input)
    *(uint2*)(ahA + (size_t)v * AH_U + 144 + c / 2) = pk;   // feat cols
    *(uint2*)(ahB + (size_t)v * AH_U + 144 + c / 2) = pk;
    *(uint2*)(hb + (size_t)v * 64 + c / 2) = pk;
    float cv = 0.f;
    if (j < net) cv = (float)(indptr[v * net + j + 1] - indptr[v * net + j]);
    ushort u = f2bu(cv);
    ((ushort*)ahA)[(size_t)v * AH_S + 256 + j] = u;
    ((ushort*)ahB)[(size_t)v * AH_S + 256 + j] = u;
}

// stage-2: only cnt cols (h/feat/hb written by stage-1 ro epilogue)
__global__ void cnt_kernel(const int* __restrict__ indptr, int net,
                           ushort* __restrict__ ahA, ushort* __restrict__ ahB)
{
    int idx = blockIdx.x * blockDim.x + threadIdx.x;   // N*32
    int v = idx >> 5;
    int j = idx & 31;
    float cv = 0.f;
    if (j < net) cv = (float)(indptr[v * net + j + 1] - indptr[v * net + j]);
    ushort u = f2bu(cv);
    ahA[(size_t)v * AH_S + 256 + j] = u;
    ahB[(size_t)v * AH_S + 256 + j] = u;
}

// pool from bf16 readout
__global__ void pool_kernel(const ushort* __restrict__ r2, float* __restrict__ pooled)
{
    int s = blockIdx.x;
    int c = threadIdx.x;
    const ushort* base = r2 + (size_t)(2 * s) * PER * 128;
    float acc = 0.f;
    for (int i = 0; i < PER; i++)
        acc += __uint_as_float(((uint)base[(size_t)i * 128 + c]) << 16);
    pooled[s * 128 + c] = acc;
}

struct GGParams {
    const float *W, *b, *wih, *whh, *bih, *bhh, *iw, *ib, *jw, *jb;
};

extern "C" void kernel_launch(void* const* d_in, const int* in_sizes, int n_in,
                              void* d_out, int out_size, void* d_ws, size_t ws_size,
                              hipStream_t stream)
{
    const float* feat    = (const float*)d_in[0];
    const int*   bi_src  = (const int*)d_in[1];
    const int*   bi_dst  = (const int*)d_in[2];
    const int*   bi_et   = (const int*)d_in[3];
    const int*   knn_src = (const int*)d_in[4];
    const int*   knn_dst = (const int*)d_in[5];
    const int*   knn_et  = (const int*)d_in[6];

    GGParams s1 { (const float*)d_in[8],  (const float*)d_in[9],  (const float*)d_in[10],
                  (const float*)d_in[11], (const float*)d_in[12], (const float*)d_in[13],
                  (const float*)d_in[14], (const float*)d_in[15], (const float*)d_in[16],
                  (const float*)d_in[17] };
    GGParams s2 { (const float*)d_in[18], (const float*)d_in[19], (const float*)d_in[20],
                  (const float*)d_in[21], (const float*)d_in[22], (const float*)d_in[23],
                  (const float*)d_in[24], (const float*)d_in[25], (const float*)d_in[26],
                  (const float*)d_in[27] };
    const float* w0 = (const float*)d_in[28];
    const float* b0 = (const float*)d_in[29];
    const float* w1 = (const float*)d_in[30];
    const float* b1 = (const float*)d_in[31];
    const float* wo = (const float*)d_in[32];
    const float* bo = (const float*)d_in[33];

    const int N = N_NODES;
    const size_t n128 = (size_t)N * 128;

    float* ws = (float*)d_ws;
    size_t off = 0;
    __hip_bfloat16* ah0 = (__hip_bfloat16*)(ws + off);  off += (size_t)N * 208;
    __hip_bfloat16* ah1 = (__hip_bfloat16*)(ws + off);  off += (size_t)N * 208;
    float* G = ws + off;                                off += 2 * n128;
    uint* hb = (uint*)(G + n128);                       // second half of G
    ushort* bfragB1 = (ushort*)(ws + off);              off += 81920 / 2;
    ushort* bfragB2 = (ushort*)(ws + off);              off += 147456 / 2;
    ushort* gruB1 = (ushort*)(ws + off);                off += 147456 / 2;
    ushort* gruB2 = (ushort*)(ws + off);                off += 147456 / 2;
    ushort* roB1 = (ushort*)(ws + off);                 off += 73728 / 2;
    ushort* roB2 = (ushort*)(ws + off);                 off += 73728 / 2;
    float* gruBias1 = ws + off;                         off += 512;
    float* gruBias2 = ws + off;                         off += 512;
    float* roBias1 = ws + off;                          off += 256;
    float* roBias2 = ws + off;                          off += 256;
    int* indptr  = (int*)(ws + off);                    off += KN_TOT + 8;
    int* cursor  = (int*)(ws + off);                    off += KN_TOT;
    int* partial = (int*)(ws + off);                    off += 4096;
    int* elist   = (int*)(ws + off);                    off += E_TOT;
    float* pooled = ws + off;                           off += 64 * 128;
    float* x1 = ws + off;                               off += 64 * 256;

    ushort* ahA = (ushort*)ah0;
    ushort* ahB = (ushort*)ah1;
    ushort* hbS = (ushort*)hb;

    // ---- fused weight prep (both stages, 1 dispatch) ----
    prep_all_kernel<<<2624, 256, 0, stream>>>(
        s1.W, s1.b, s1.wih, s1.whh, s1.bih, s1.bhh, s1.iw, s1.ib, s1.jw, s1.jb,
        s2.W, s2.b, s2.wih, s2.whh, s2.bih, s2.bhh, s2.iw, s2.ib, s2.jw, s2.jb,
        bfragB1, gruB1, gruBias1, roB1, roBias1,
        bfragB2, gruB2, gruBias2, roB2, roBias2);

    // ---- merged CSR build ----
    hipMemsetAsync(cursor, 0, KN_TOT * sizeof(int), stream);
    hist2_kernel<<<(E_TOT + 255) / 256, 256, 0, stream>>>(bi_dst, bi_et, knn_dst, knn_et, cursor);
    scan1_kernel<<<KN_TOT / 256, 256, 0, stream>>>(cursor, indptr, partial);
    scan2b_kernel<<<1, 256, 0, stream>>>(partial, KN_TOT / 256, indptr + KN_TOT, E_TOT);
    scan3c_kernel<<<KN_TOT / 256, 256, 0, stream>>>(indptr, partial, cursor);
    fill2_kernel<<<(E_TOT + 255) / 256, 256, 0, stream>>>(bi_src, bi_dst, bi_et,
                                                          knn_src, knn_dst, knn_et,
                                                          cursor, elist);

    // ================= Stage 1: bond graph (5 etypes), Fin=64 =================
    pad_cnt_kernel<<<(N * 32) / 256, 256, 0, stream>>>(feat, indptr, 5,
                                                       (uint*)ahA, (uint*)ahB, hb, 64);
    {
        ushort* ahIn = ahA;
        ushort* ahOut = ahB;
        for (int step = 0; step < 2; step++) {
            msg_kernel<5><<<N / 32, 256, 0, stream>>>(hb, indptr, elist, bfragB1, ahIn);
            dim3 g(N / 128, 4);
            gru_gemm_kernel<<<g, 256, 0, stream>>>(ahIn, gruB1, gruBias1, ahOut, hbS);
            ushort* t = ahIn; ahIn = ahOut; ahOut = t;
        }
        // ahIn == ahA here; stage-1 readout reads ahA, writes stage-2 operands into ahB
        dim3 gr(N / 128, 2);
        ro_gemm_kernel<<<gr, 256, 0, stream>>>(ahIn + 128, roB1, roBias1,
                                               nullptr, ahB, hbS);
    }

    // ================= Stage 2: knn graph (9 etypes), ping-pong starts at ahB ==========
    cnt_kernel<<<(N * 32) / 256, 256, 0, stream>>>(indptr + KN_BI, 9, ahA, ahB);
    __hip_bfloat16* r2b = (__hip_bfloat16*)G;   // first half of G
    {
        ushort* ahIn = ahB;
        ushort* ahOut = ahA;
        for (int step = 0; step < 2; step++) {
            msg_kernel<9><<<N / 32, 256, 0, stream>>>(hb, indptr + KN_BI, elist, bfragB2, ahIn);
            dim3 g(N / 128, 4);
            gru_gemm_kernel<<<g, 256, 0, stream>>>(ahIn, gruB2, gruBias2, ahOut, hbS);
            ushort* t = ahIn; ahIn = ahOut; ahOut = t;
        }
        // ahIn == ahB here: h (latest), cnt, feat (from stage-1 ro) all present
        dim3 gr(N / 128, 2);
        ro_gemm_kernel<<<gr, 256, 0, stream>>>(ahIn + 128, roB2, roBias2,
                                               (ushort*)r2b, nullptr, nullptr);
    }

    // ================= Stage 3: ligand pooling + MLP =================
    pool_kernel<<<64, 128, 0, stream>>>((const ushort*)r2b, pooled);
    {
        dim3 g1(1, 4);
        gemm_kernel<<<g1, 256, 0, stream>>>(pooled, 128, w0, 256, b0, x1, 256, 128, 1);
    }
    mlp2_kernel<<<1, 256, 0, stream>>>(x1, w1, b1, wo, bo, (float*)d_out);
}

// Round 17
// 704.374 us; speedup vs baseline: 1.3198x; 1.3198x over previous
//
#include <hip/hip_runtime.h>
#include <hip/hip_bf16.h>

#define N_NODES 50176
#define PER 392
#define E_BI (N_NODES * 4)      // 200704
#define E_KNN (N_NODES * 16)    // 802816
#define E_TOT (E_BI + E_KNN)    // 1003520
#define KN_BI (N_NODES * 5)     // 250880
#define KN_TOT (N_NODES * 14)   // 702464
#define AH_S 416                // ah row stride (shorts): [a(128)|h(128)|cnt(32)|feat(128)]
#define AH_U 208                // ... in uints

typedef __attribute__((ext_vector_type(8))) short short8;
typedef __attribute__((ext_vector_type(4))) float float4v;
typedef unsigned int uint;
typedef unsigned short ushort;

__device__ __forceinline__ float sigmoidf_(float x) { return 1.f / (1.f + __expf(-x)); }
__device__ __forceinline__ ushort f2bu(float x) {
    __hip_bfloat16 t = __float2bfloat16(x);
    return *reinterpret_cast<ushort*>(&t);
}
__device__ __forceinline__ float blo(uint u) { return __uint_as_float(u << 16); }
__device__ __forceinline__ float bhi(uint u) { return __uint_as_float(u & 0xFFFF0000u); }

// direct global->LDS DMA, 16B per lane; LDS dest = wave-uniform base + lane*16
__device__ __forceinline__ void gld_lds16(const ushort* g, ushort* l)
{
    __builtin_amdgcn_global_load_lds(
        (const __attribute__((address_space(1))) void*)g,
        (__attribute__((address_space(3))) void*)l, 16, 0, 0);
}

// ================= fused aggregate + per-etype transform (v4 — measured optimum) ======
// Block = 32 node rows, 256 threads: 8 threads/row (16 ch each, 2x16B loads/edge).
// NOTE: r8 (thread reshape), r11 (parity split), r12 (pairwise unroll) all regressed
// vs this exact loop body — do not reshape the gather.
template<int NET>
__global__ __launch_bounds__(256) void msg_kernel(
    const uint* __restrict__ hb,           // [N][64] uints (h bf16 packed)
    const int* __restrict__ indptr,        // [N*NET+1] slice (absolute into elist)
    const int* __restrict__ elist,
    const ushort* __restrict__ Bfrag,      // fragment-ordered weights
    ushort* __restrict__ aout)             // target ah buffer; write cols 0..127
{
    __shared__ ushort As[4][32][40];       // 10.25 KB, chunk-major, 80B rows
    const int tid = threadIdx.x;
    const int bm = blockIdx.x * 32;
    const int wave = tid >> 6, lane = tid & 63;
    const int quad = lane >> 4, lrow = lane & 15;
    const int wr = wave & 1, wc = wave >> 1;
    const int r = tid >> 3;                // node row 0..31
    const int oct = tid & 7;               // 16-ch group
    const int v = bm + r;

    uint* AsU = (uint*)As;                 // [ch][r][20] uints

    float4v acc[4] = {};

    for (int et = 0; et < NET; et++) {
        const int beg = indptr[v * NET + et], end = indptr[v * NET + et + 1];
        float av[16];
#pragma unroll
        for (int i = 0; i < 16; i++) av[i] = 0.f;

        for (int j = beg; j < end; j++) {
            int src = elist[j];
            const uint4* hp = (const uint4*)(hb + (size_t)src * 64 + oct * 8);
            uint4 u0 = hp[0];
            uint4 u1 = hp[1];
            av[0] += blo(u0.x); av[1] += bhi(u0.x);
            av[2] += blo(u0.y); av[3] += bhi(u0.y);
            av[4] += blo(u0.z); av[5] += bhi(u0.z);
            av[6] += blo(u0.w); av[7] += bhi(u0.w);
            av[8]  += blo(u1.x); av[9]  += bhi(u1.x);
            av[10] += blo(u1.y); av[11] += bhi(u1.y);
            av[12] += blo(u1.z); av[13] += bhi(u1.z);
            av[14] += blo(u1.w); av[15] += bhi(u1.w);
        }

        __syncthreads();                   // previous etype's As reads complete
        {
            int base = ((oct >> 1) * 32 + r) * 20 + (oct & 1) * 8;
#pragma unroll
            for (int u = 0; u < 8; u++)
                AsU[base + u] = (uint)f2bu(av[2 * u]) | ((uint)f2bu(av[2 * u + 1]) << 16);
        }
        __syncthreads();

#pragma unroll
        for (int ch = 0; ch < 4; ch++) {
            short8 af = *(const short8*)&As[ch][wr * 16 + lrow][quad * 8];
            const ushort* bp = Bfrag + ((size_t)(((et * 4 + ch) * 2 + wc) * 4) << 9) + lane * 8;
#pragma unroll
            for (int j2 = 0; j2 < 4; j2++) {
                short8 bfr = *(const short8*)(bp + j2 * 512);
                acc[j2] = __builtin_amdgcn_mfma_f32_16x16x32_bf16(af, bfr, acc[j2], 0, 0, 0);
            }
        }
    }

#pragma unroll
    for (int j2 = 0; j2 < 4; j2++) {
        int col = wc * 64 + j2 * 16 + lrow;
#pragma unroll
        for (int rr = 0; rr < 4; rr++) {
            size_t row = (size_t)(bm + wr * 16 + quad * 4 + rr);
            aout[row * AH_S + col] = f2bu(acc[j2][rr]);
        }
    }
}

// ================= GRU GEMM with fused gate epilogue (ping-pong, race-free) ============
__global__ __launch_bounds__(256) void gru_gemm_kernel(
    const ushort* __restrict__ A,          // ahIn base, lda AH_S
    const ushort* __restrict__ Bt,         // gruB [512][288] permuted
    const float* __restrict__ bias,        // [512] permuted
    ushort* __restrict__ ahOut, ushort* __restrict__ hbS)
{
    __shared__ ushort As[128 * 32];
    __shared__ ushort Bs[128 * 32];
    const int tid = threadIdx.x;
    const int bm = blockIdx.x * 128;
    const int bn = blockIdx.y * 128;
    const int wave = tid >> 6, lane = tid & 63;
    const int quad = lane >> 4, lrow = lane & 15;
    const int wr = wave & 1, wc = wave >> 1;

    float4v acc[4][4] = {};

    for (int k0 = 0; k0 < 288; k0 += 32) {
        __syncthreads();
#pragma unroll
        for (int p = 0; p < 2; p++) {
            int lin = p * 256 + tid;
            int r = lin >> 2;
            int kc = (lin & 3) * 8;
            int wb = (p * 256 + wave * 64) * 8;       // wave-uniform LDS base (ushorts)
            gld_lds16(A + (size_t)(bm + r) * AH_S + k0 + kc, &As[wb]);
            gld_lds16(Bt + (size_t)(bn + r) * 288 + k0 + kc, &Bs[wb]);
        }
        __syncthreads();
        short8 af[4], bfr[4];
#pragma unroll
        for (int i = 0; i < 4; i++)
            af[i] = *(const short8*)&As[(wr * 64 + i * 16 + lrow) * 32 + quad * 8];
#pragma unroll
        for (int j = 0; j < 4; j++)
            bfr[j] = *(const short8*)&Bs[(wc * 64 + j * 16 + lrow) * 32 + quad * 8];
#pragma unroll
        for (int i = 0; i < 4; i++)
#pragma unroll
            for (int j = 0; j < 4; j++)
                acc[i][j] = __builtin_amdgcn_mfma_f32_16x16x32_bf16(af[i], bfr[j], acc[i][j], 0, 0, 0);
    }

    const int ch = (bn >> 7) * 32 + wc * 16 + lrow;
    const float b0 = bias[bn + wc * 64 + lrow];
    const float b1 = bias[bn + wc * 64 + 16 + lrow];
    const float b2 = bias[bn + wc * 64 + 32 + lrow];
    const float b3 = bias[bn + wc * 64 + 48 + lrow];
#pragma unroll
    for (int i = 0; i < 4; i++) {
#pragma unroll
        for (int r = 0; r < 4; r++) {
            size_t row = (size_t)(bm + wr * 64 + i * 16 + quad * 4 + r);
            float rr = sigmoidf_(acc[i][0][r] + b0);
            float zz = sigmoidf_(acc[i][1][r] + b1);
            float nn = tanhf(acc[i][2][r] + b2 + rr * (acc[i][3][r] + b3));
            float hold = __uint_as_float(((uint)A[row * AH_S + 128 + ch]) << 16);
            float hnew = (1.f - zz) * nn + zz * hold;
            ushort hu = f2bu(hnew);
            ahOut[row * AH_S + 128 + ch] = hu;
            hbS[row * 128 + ch] = hu;
        }
    }
}

// ================= readout GEMM with fused sigmoid-mul epilogue =================
// Stage-1 mode (ahx != null): write o into ahx (the OTHER ping-pong buffer — never
// read by this kernel, so race-free): h-cols + feat-cols, plus hb.
// Stage-2 mode (rb != null): write bf16 rout only.
__global__ __launch_bounds__(256) void ro_gemm_kernel(
    const ushort* __restrict__ A,
    const ushort* __restrict__ Bt,         // [256][288]
    const float* __restrict__ bias,        // [256] permuted
    ushort* __restrict__ rb,
    ushort* __restrict__ ahx, ushort* __restrict__ hbS)
{
    __shared__ ushort As[128 * 32];
    __shared__ ushort Bs[128 * 32];
    const int tid = threadIdx.x;
    const int bm = blockIdx.x * 128;
    const int bn = blockIdx.y * 128;
    const int wave = tid >> 6, lane = tid & 63;
    const int quad = lane >> 4, lrow = lane & 15;
    const int wr = wave & 1, wc = wave >> 1;

    float4v acc[4][4] = {};

    for (int k0 = 0; k0 < 288; k0 += 32) {
        __syncthreads();
#pragma unroll
        for (int p = 0; p < 2; p++) {
            int lin = p * 256 + tid;
            int r = lin >> 2;
            int kc = (lin & 3) * 8;
            int wb = (p * 256 + wave * 64) * 8;
            gld_lds16(A + (size_t)(bm + r) * AH_S + k0 + kc, &As[wb]);
            gld_lds16(Bt + (size_t)(bn + r) * 288 + k0 + kc, &Bs[wb]);
        }
        __syncthreads();
        short8 af[4], bfr[4];
#pragma unroll
        for (int i = 0; i < 4; i++)
            af[i] = *(const short8*)&As[(wr * 64 + i * 16 + lrow) * 32 + quad * 8];
#pragma unroll
        for (int j = 0; j < 4; j++)
            bfr[j] = *(const short8*)&Bs[(wc * 64 + j * 16 + lrow) * 32 + quad * 8];
#pragma unroll
        for (int i = 0; i < 4; i++)
#pragma unroll
            for (int j = 0; j < 4; j++)
                acc[i][j] = __builtin_amdgcn_mfma_f32_16x16x32_bf16(af[i], bfr[j], acc[i][j], 0, 0, 0);
    }

    const int c0 = (bn >> 7) * 64 + wc * 32 + lrow;
    const int c1 = c0 + 16;
    const float bu0 = bias[bn + wc * 64 + lrow];
    const float bv0 = bias[bn + wc * 64 + 16 + lrow];
    const float bu1 = bias[bn + wc * 64 + 32 + lrow];
    const float bv1 = bias[bn + wc * 64 + 48 + lrow];
#pragma unroll
    for (int i = 0; i < 4; i++) {
#pragma unroll
        for (int r = 0; r < 4; r++) {
            size_t row = (size_t)(bm + wr * 64 + i * 16 + quad * 4 + r);
            float o0 = sigmoidf_(acc[i][0][r] + bu0) * (acc[i][1][r] + bv0);
            float o1 = sigmoidf_(acc[i][2][r] + bu1) * (acc[i][3][r] + bv1);
            ushort u0 = f2bu(o0), u1 = f2bu(o1);
            if (rb) {
                rb[row * 128 + c0] = u0;
                rb[row * 128 + c1] = u1;
            }
            if (ahx) {
                ahx[row * AH_S + 128 + c0] = u0;   // stage-2 h init
                ahx[row * AH_S + 128 + c1] = u1;
                ahx[row * AH_S + 288 + c0] = u0;   // stage-2 feat cols
                ahx[row * AH_S + 288 + c1] = u1;
                hbS[row * 128 + c0] = u0;
                hbS[row * 128 + c1] = u1;
            }
        }
    }
}

// ================= small fp32 GEMM (stage-3 MLP) =================
__global__ __launch_bounds__(256) void gemm_kernel(
    const float* __restrict__ A, int lda,
    const float* __restrict__ B, int ldb,
    const float* __restrict__ bias,
    float* __restrict__ C, int ldc,
    int K, int act)
{
    __shared__ float As[32][68];
    __shared__ float Bs[32][68];
    const int tid = threadIdx.x;
    const int bm = blockIdx.x * 64;
    const int bn = blockIdx.y * 64;
    const int tm = (tid & 15) * 4;
    const int tn = (tid >> 4) * 4;
    float acc[4][4] = {};

    for (int k0 = 0; k0 < K; k0 += 32) {
#pragma unroll
        for (int p = 0; p < 2; p++) {
            int lin = p * 256 + tid;
            int ar = lin >> 3;
            int ac = (lin & 7) << 2;
            float4 av = *(const float4*)(A + (size_t)(bm + ar) * lda + (k0 + ac));
            As[ac + 0][ar] = av.x;
            As[ac + 1][ar] = av.y;
            As[ac + 2][ar] = av.z;
            As[ac + 3][ar] = av.w;
            int br = lin >> 4;
            int bc = (lin & 15) << 2;
            *(float4*)&Bs[br][bc] = *(const float4*)(B + (size_t)(k0 + br) * ldb + (bn + bc));
        }
        __syncthreads();
#pragma unroll
        for (int k = 0; k < 32; k++) {
            float4 a4 = *(const float4*)&As[k][tm];
            float4 b4 = *(const float4*)&Bs[k][tn];
            float av[4] = {a4.x, a4.y, a4.z, a4.w};
            float bv[4] = {b4.x, b4.y, b4.z, b4.w};
#pragma unroll
            for (int i = 0; i < 4; i++)
#pragma unroll
                for (int j = 0; j < 4; j++)
                    acc[i][j] += av[i] * bv[j];
        }
        __syncthreads();
    }
#pragma unroll
    for (int i = 0; i < 4; i++) {
        size_t row = (size_t)(bm + tm + i);
#pragma unroll
        for (int j = 0; j < 4; j++) {
            int col = bn + tn + j;
            float val = acc[i][j] + (bias ? bias[col] : 0.f);
            if (act == 1) val = fmaxf(val, 0.f);
            C[row * ldc + col] = val;
        }
    }
}

// ================= final dot: out[row] = x2[row,:] . wo + bo =================
__global__ void out_kernel(const float* __restrict__ x2, const float* __restrict__ wo,
                           const float* __restrict__ bo, float* __restrict__ out)
{
    int row = blockIdx.x;
    int t = threadIdx.x;         // 64 threads = one wave
    float s = x2[row * 128 + t] * wo[t] + x2[row * 128 + 64 + t] * wo[64 + t];
#pragma unroll
    for (int off = 32; off; off >>= 1) s += __shfl_down(s, off);
    if (t == 0) out[row] = s + bo[0];
}

// ================= fused weight prep (both stages, one dispatch) =================
__device__ __forceinline__ void prep_bfrag_item(const float* W, ushort* Bf, int idx)
{
    int m = idx & 7;
    int lane = (idx >> 3) & 63;
    int f = idx >> 9;
    int j = f & 3; f >>= 2;
    int wc = f & 1; f >>= 1;
    int ch = f & 3;
    int et = f >> 2;
    int quad = lane >> 4, lrow = lane & 15;
    int k = ch * 32 + quad * 8 + m;
    int c = wc * 64 + j * 16 + lrow;
    Bf[idx] = f2bu(W[et * 16384 + k * 128 + c]);
}

__device__ __forceinline__ void prep_gru_item(const float* wih, const float* whh,
                                              const float* bih, const float* bhh,
                                              const float* b, int net,
                                              ushort* Bt, float* bias, int idx)
{
    int p = idx / 288;
    int k = idx - p * 288;
    int g = (p >> 4) & 3;
    int c = (p >> 7) * 32 + ((p >> 6) & 1) * 16 + (p & 15);
    float val = 0.f;
    if (k < 128) {
        if (g == 0)      val = wih[k * 384 + c];
        else if (g == 1) val = wih[k * 384 + 128 + c];
        else if (g == 2) val = wih[k * 384 + 256 + c];
    } else if (k < 256) {
        int kk = k - 128;
        if (g == 0)      val = whh[kk * 384 + c];
        else if (g == 1) val = whh[kk * 384 + 128 + c];
        else if (g == 3) val = whh[kk * 384 + 256 + c];
    } else {
        int j = k - 256;
        if (j < net && g < 3) {
            int col = g * 128 + c;
            float s = 0.f;
            for (int kk = 0; kk < 128; kk++) s += b[j * 128 + kk] * wih[kk * 384 + col];
            val = s;
        }
    }
    Bt[idx] = f2bu(val);
    if (k == 0) {
        float bv;
        if (g == 0)      bv = bih[c] + bhh[c];
        else if (g == 1) bv = bih[128 + c] + bhh[128 + c];
        else if (g == 2) bv = bih[256 + c];
        else             bv = bhh[256 + c];
        bias[p] = bv;
    }
}

__device__ __forceinline__ void prep_ro_item(const float* iw, const float* jw,
                                             const float* ib, const float* jb,
                                             int Fin, ushort* Bt, float* bias, int idx)
{
    int p = idx / 288;
    int k = idx - p * 288;
    int j = (p >> 4) & 3;
    int s = j & 1;
    int c = ((p >> 7) & 1) * 64 + ((p >> 6) & 1) * 32 + (j >> 1) * 16 + (p & 15);
    float val = 0.f;
    if (k < 128) {
        val = s ? jw[k * 128 + c] : iw[k * 128 + c];
    } else if (k >= 160) {
        int kf = k - 160;
        if (kf < Fin && s == 0) val = iw[(128 + kf) * 128 + c];
    }
    Bt[idx] = f2bu(val);
    if (k == 0) bias[p] = s ? jb[c] : ib[c];
}

// sections: bf1 81920 | gru1 147456 | ro1 73728 | bf2 147456 | gru2 147456 | ro2 73728
__global__ __launch_bounds__(256) void prep_all_kernel(
    const float* W1, const float* b1, const float* wih1, const float* whh1,
    const float* bih1, const float* bhh1, const float* iw1, const float* ib1,
    const float* jw1, const float* jb1,
    const float* W2, const float* b2, const float* wih2, const float* whh2,
    const float* bih2, const float* bhh2, const float* iw2, const float* ib2,
    const float* jw2, const float* jb2,
    ushort* bf1, ushort* gru1, float* gb1, ushort* ro1, float* rb1,
    ushort* bf2, ushort* gru2, float* gb2, ushort* ro2, float* rb2)
{
    int gid = blockIdx.x * 256 + threadIdx.x;
    if (gid < 81920)            prep_bfrag_item(W1, bf1, gid);
    else if (gid < 229376)      prep_gru_item(wih1, whh1, bih1, bhh1, b1, 5, gru1, gb1, gid - 81920);
    else if (gid < 303104)      prep_ro_item(iw1, jw1, ib1, jb1, 64, ro1, rb1, gid - 229376);
    else if (gid < 450560)      prep_bfrag_item(W2, bf2, gid - 303104);
    else if (gid < 598016)      prep_gru_item(wih2, whh2, bih2, bhh2, b2, 9, gru2, gb2, gid - 450560);
    else                        prep_ro_item(iw2, jw2, ib2, jb2, 128, ro2, rb2, gid - 598016);
}

// ================= merged CSR build =================
__global__ void hist2_kernel(const int* __restrict__ bd, const int* __restrict__ be,
                             const int* __restrict__ kd, const int* __restrict__ ke,
                             int* __restrict__ counts)
{
    int e = blockIdx.x * blockDim.x + threadIdx.x;
    if (e >= E_TOT) return;
    if (e < E_BI) atomicAdd(&counts[bd[e] * 5 + be[e]], 1);
    else { int i = e - E_BI; atomicAdd(&counts[KN_BI + kd[i] * 9 + ke[i]], 1); }
}

__global__ void scan1_kernel(const int* __restrict__ counts, int* __restrict__ local_ex,
                             int* __restrict__ partial)
{
    __shared__ int s[256];
    int t = threadIdx.x;
    int i = blockIdx.x * 256 + t;
    int v = counts[i];
    s[t] = v;
    __syncthreads();
    for (int off = 1; off < 256; off <<= 1) {
        int x = 0;
        if (t >= off) x = s[t - off];
        __syncthreads();
        if (t >= off) s[t] += x;
        __syncthreads();
    }
    local_ex[i] = s[t] - v;
    if (t == 255) partial[blockIdx.x] = s[255];
}

__global__ void scan2b_kernel(int* __restrict__ partial, int nb, int* __restrict__ last, int E)
{
    __shared__ int s[256];
    int t = threadIdx.x;
    int loc[11];
    int sum = 0;
#pragma unroll
    for (int q = 0; q < 11; q++) {
        int idx = t * 11 + q;
        int v = (idx < nb) ? partial[idx] : 0;
        loc[q] = sum; sum += v;
    }
    s[t] = sum;
    __syncthreads();
    for (int off = 1; off < 256; off <<= 1) {
        int x = 0;
        if (t >= off) x = s[t - off];
        __syncthreads();
        if (t >= off) s[t] += x;
        __syncthreads();
    }
    int excl = s[t] - sum;
#pragma unroll
    for (int q = 0; q < 11; q++) {
        int idx = t * 11 + q;
        if (idx < nb) partial[idx] = excl + loc[q];
    }
    if (t == 0) *last = E;
}

__global__ void scan3c_kernel(int* __restrict__ indptr, const int* __restrict__ partial,
                              int* __restrict__ cursor)
{
    int i = blockIdx.x * 256 + threadIdx.x;
    int v = indptr[i] + partial[blockIdx.x];
    indptr[i] = v;
    cursor[i] = v;
}

__global__ void fill2_kernel(const int* __restrict__ bs, const int* __restrict__ bd,
                             const int* __restrict__ be,
                             const int* __restrict__ ks, const int* __restrict__ kd,
                             const int* __restrict__ ke,
                             int* __restrict__ cursor, int* __restrict__ elist)
{
    int e = blockIdx.x * blockDim.x + threadIdx.x;
    if (e >= E_TOT) return;
    if (e < E_BI) {
        int pos = atomicAdd(&cursor[bd[e] * 5 + be[e]], 1);
        elist[pos] = bs[e];
    } else {
        int i = e - E_BI;
        int pos = atomicAdd(&cursor[KN_BI + kd[i] * 9 + ke[i]], 1);
        elist[pos] = ks[i];
    }
}

// ================= elementwise =================
// stage-1 pad: feat fp32 -> ahA h-cols + feat cols (both) + hb + cnt cols (both)
__global__ void pad_cnt_kernel(const float* __restrict__ fsrc,
                               const int* __restrict__ indptr, int net,
                               uint* __restrict__ ahA, uint* __restrict__ ahB,
                               uint* __restrict__ hb, int Fin)
{
    int idx = blockIdx.x * blockDim.x + threadIdx.x;   // N*32
    int v = idx >> 5;
    int j = idx & 31;
    int c = j * 4;
    float4 val = make_float4(0.f, 0.f, 0.f, 0.f);
    if (c < Fin) val = *(const float4*)(fsrc + (size_t)v * Fin + c);
    uint2 pk;
    pk.x = (uint)f2bu(val.x) | ((uint)f2bu(val.y) << 16);
    pk.y = (uint)f2bu(val.z) | ((uint)f2bu(val.w) << 16);
    *(uint2*)(ahA + (size_t)v * AH_U + 64 + c / 2) = pk;    // h cols (step-0 input)
    *(uint2*)(ahA + (size_t)v * AH_U + 144 + c / 2) = pk;   // feat cols
    *(uint2*)(ahB + (size_t)v * AH_U + 144 + c / 2) = pk;
    *(uint2*)(hb + (size_t)v * 64 + c / 2) = pk;
    float cv = 0.f;
    if (j < net) cv = (float)(indptr[v * net + j + 1] - indptr[v * net + j]);
    ushort u = f2bu(cv);
    ((ushort*)ahA)[(size_t)v * AH_S + 256 + j] = u;
    ((ushort*)ahB)[(size_t)v * AH_S + 256 + j] = u;
}

// stage-2: only cnt cols (h/feat/hb written by stage-1 ro epilogue)
__global__ void cnt_kernel(const int* __restrict__ indptr, int net,
                           ushort* __restrict__ ahA, ushort* __restrict__ ahB)
{
    int idx = blockIdx.x * blockDim.x + threadIdx.x;   // N*32
    int v = idx >> 5;
    int j = idx & 31;
    float cv = 0.f;
    if (j < net) cv = (float)(indptr[v * net + j + 1] - indptr[v * net + j]);
    ushort u = f2bu(cv);
    ahA[(size_t)v * AH_S + 256 + j] = u;
    ahB[(size_t)v * AH_S + 256 + j] = u;
}

// pool from bf16 readout
__global__ void pool_kernel(const ushort* __restrict__ r2, float* __restrict__ pooled)
{
    int s = blockIdx.x;
    int c = threadIdx.x;
    const ushort* base = r2 + (size_t)(2 * s) * PER * 128;
    float acc = 0.f;
    for (int i = 0; i < PER; i++)
        acc += __uint_as_float(((uint)base[(size_t)i * 128 + c]) << 16);
    pooled[s * 128 + c] = acc;
}

struct GGParams {
    const float *W, *b, *wih, *whh, *bih, *bhh, *iw, *ib, *jw, *jb;
};

extern "C" void kernel_launch(void* const* d_in, const int* in_sizes, int n_in,
                              void* d_out, int out_size, void* d_ws, size_t ws_size,
                              hipStream_t stream)
{
    const float* feat    = (const float*)d_in[0];
    const int*   bi_src  = (const int*)d_in[1];
    const int*   bi_dst  = (const int*)d_in[2];
    const int*   bi_et   = (const int*)d_in[3];
    const int*   knn_src = (const int*)d_in[4];
    const int*   knn_dst = (const int*)d_in[5];
    const int*   knn_et  = (const int*)d_in[6];

    GGParams s1 { (const float*)d_in[8],  (const float*)d_in[9],  (const float*)d_in[10],
                  (const float*)d_in[11], (const float*)d_in[12], (const float*)d_in[13],
                  (const float*)d_in[14], (const float*)d_in[15], (const float*)d_in[16],
                  (const float*)d_in[17] };
    GGParams s2 { (const float*)d_in[18], (const float*)d_in[19], (const float*)d_in[20],
                  (const float*)d_in[21], (const float*)d_in[22], (const float*)d_in[23],
                  (const float*)d_in[24], (const float*)d_in[25], (const float*)d_in[26],
                  (const float*)d_in[27] };
    const float* w0 = (const float*)d_in[28];
    const float* b0 = (const float*)d_in[29];
    const float* w1 = (const float*)d_in[30];
    const float* b1 = (const float*)d_in[31];
    const float* wo = (const float*)d_in[32];
    const float* bo = (const float*)d_in[33];

    const int N = N_NODES;
    const size_t n128 = (size_t)N * 128;

    float* ws = (float*)d_ws;
    size_t off = 0;
    __hip_bfloat16* ah0 = (__hip_bfloat16*)(ws + off);  off += (size_t)N * 208;
    __hip_bfloat16* ah1 = (__hip_bfloat16*)(ws + off);  off += (size_t)N * 208;
    float* G = ws + off;                                off += 2 * n128;
    uint* hb = (uint*)(G + n128);                       // second half of G
    ushort* bfragB1 = (ushort*)(ws + off);              off += 81920 / 2;
    ushort* bfragB2 = (ushort*)(ws + off);              off += 147456 / 2;
    ushort* gruB1 = (ushort*)(ws + off);                off += 147456 / 2;
    ushort* gruB2 = (ushort*)(ws + off);                off += 147456 / 2;
    ushort* roB1 = (ushort*)(ws + off);                 off += 73728 / 2;
    ushort* roB2 = (ushort*)(ws + off);                 off += 73728 / 2;
    float* gruBias1 = ws + off;                         off += 512;
    float* gruBias2 = ws + off;                         off += 512;
    float* roBias1 = ws + off;                          off += 256;
    float* roBias2 = ws + off;                          off += 256;
    int* indptr  = (int*)(ws + off);                    off += KN_TOT + 8;
    int* cursor  = (int*)(ws + off);                    off += KN_TOT;
    int* partial = (int*)(ws + off);                    off += 4096;
    int* elist   = (int*)(ws + off);                    off += E_TOT;
    float* pooled = ws + off;                           off += 64 * 128;
    float* x1 = ws + off;                               off += 64 * 256;
    float* x2 = ws + off;                               off += 64 * 128;

    ushort* ahA = (ushort*)ah0;
    ushort* ahB = (ushort*)ah1;
    ushort* hbS = (ushort*)hb;

    // ---- fused weight prep (both stages, 1 dispatch) ----
    prep_all_kernel<<<2624, 256, 0, stream>>>(
        s1.W, s1.b, s1.wih, s1.whh, s1.bih, s1.bhh, s1.iw, s1.ib, s1.jw, s1.jb,
        s2.W, s2.b, s2.wih, s2.whh, s2.bih, s2.bhh, s2.iw, s2.ib, s2.jw, s2.jb,
        bfragB1, gruB1, gruBias1, roB1, roBias1,
        bfragB2, gruB2, gruBias2, roB2, roBias2);

    // ---- merged CSR build ----
    hipMemsetAsync(cursor, 0, KN_TOT * sizeof(int), stream);
    hist2_kernel<<<(E_TOT + 255) / 256, 256, 0, stream>>>(bi_dst, bi_et, knn_dst, knn_et, cursor);
    scan1_kernel<<<KN_TOT / 256, 256, 0, stream>>>(cursor, indptr, partial);
    scan2b_kernel<<<1, 256, 0, stream>>>(partial, KN_TOT / 256, indptr + KN_TOT, E_TOT);
    scan3c_kernel<<<KN_TOT / 256, 256, 0, stream>>>(indptr, partial, cursor);
    fill2_kernel<<<(E_TOT + 255) / 256, 256, 0, stream>>>(bi_src, bi_dst, bi_et,
                                                          knn_src, knn_dst, knn_et,
                                                          cursor, elist);

    // ================= Stage 1: bond graph (5 etypes), Fin=64 =================
    pad_cnt_kernel<<<(N * 32) / 256, 256, 0, stream>>>(feat, indptr, 5,
                                                       (uint*)ahA, (uint*)ahB, hb, 64);
    {
        ushort* ahIn = ahA;
        ushort* ahOut = ahB;
        for (int step = 0; step < 2; step++) {
            msg_kernel<5><<<N / 32, 256, 0, stream>>>(hb, indptr, elist, bfragB1, ahIn);
            dim3 g(N / 128, 4);
            gru_gemm_kernel<<<g, 256, 0, stream>>>(ahIn, gruB1, gruBias1, ahOut, hbS);
            ushort* t = ahIn; ahIn = ahOut; ahOut = t;
        }
        // ahIn == ahA here; stage-1 readout reads ahA, writes stage-2 operands into ahB
        dim3 gr(N / 128, 2);
        ro_gemm_kernel<<<gr, 256, 0, stream>>>(ahIn + 128, roB1, roBias1,
                                               nullptr, ahB, hbS);
    }

    // ================= Stage 2: knn graph (9 etypes), ping-pong starts at ahB ==========
    cnt_kernel<<<(N * 32) / 256, 256, 0, stream>>>(indptr + KN_BI, 9, ahA, ahB);
    __hip_bfloat16* r2b = (__hip_bfloat16*)G;   // first half of G
    {
        ushort* ahIn = ahB;
        ushort* ahOut = ahA;
        for (int step = 0; step < 2; step++) {
            msg_kernel<9><<<N / 32, 256, 0, stream>>>(hb, indptr + KN_BI, elist, bfragB2, ahIn);
            dim3 g(N / 128, 4);
            gru_gemm_kernel<<<g, 256, 0, stream>>>(ahIn, gruB2, gruBias2, ahOut, hbS);
            ushort* t = ahIn; ahIn = ahOut; ahOut = t;
        }
        // ahIn == ahB here: h (latest), cnt, feat (from stage-1 ro) all present
        dim3 gr(N / 128, 2);
        ro_gemm_kernel<<<gr, 256, 0, stream>>>(ahIn + 128, roB2, roBias2,
                                               (ushort*)r2b, nullptr, nullptr);
    }

    // ================= Stage 3: ligand pooling + MLP =================
    pool_kernel<<<64, 128, 0, stream>>>((const ushort*)r2b, pooled);
    {
        dim3 g1(1, 4);
        gemm_kernel<<<g1, 256, 0, stream>>>(pooled, 128, w0, 256, b0, x1, 256, 128, 1);
        dim3 g2(1, 2);
        gemm_kernel<<<g2, 256, 0, stream>>>(x1, 256, w1, 128, b1, x2, 128, 256, 1);
    }
    out_kernel<<<64, 64, 0, stream>>>(x2, wo, bo, (float*)d_out);
}

// Round 18
// 689.626 us; speedup vs baseline: 1.3480x; 1.0214x over previous
//
#include <hip/hip_runtime.h>
#include <hip/hip_bf16.h>

#define N_NODES 50176
#define PER 392
#define E_BI (N_NODES * 4)      // 200704
#define E_KNN (N_NODES * 16)    // 802816
#define E_TOT (E_BI + E_KNN)    // 1003520
#define KN_BI (N_NODES * 5)     // 250880
#define KN_TOT (N_NODES * 14)   // 702464
#define AH_S 416                // ah row stride (shorts): [a(128)|h(128)|cnt(32)|feat(128)]
#define AH_U 208                // ... in uints

typedef __attribute__((ext_vector_type(8))) short short8;
typedef __attribute__((ext_vector_type(4))) float float4v;
typedef unsigned int uint;
typedef unsigned short ushort;

__device__ __forceinline__ float sigmoidf_(float x) { return 1.f / (1.f + __expf(-x)); }
__device__ __forceinline__ ushort f2bu(float x) {
    __hip_bfloat16 t = __float2bfloat16(x);
    return *reinterpret_cast<ushort*>(&t);
}
__device__ __forceinline__ float blo(uint u) { return __uint_as_float(u << 16); }
__device__ __forceinline__ float bhi(uint u) { return __uint_as_float(u & 0xFFFF0000u); }

// direct global->LDS DMA, 16B per lane; LDS dest = wave-uniform base + lane*16
__device__ __forceinline__ void gld_lds16(const ushort* g, ushort* l)
{
    __builtin_amdgcn_global_load_lds(
        (const __attribute__((address_space(1))) void*)g,
        (__attribute__((address_space(3))) void*)l, 16, 0, 0);
}

// ================= fused aggregate + per-etype transform (v4 — measured optimum) ======
// Block = 32 node rows, 256 threads: 8 threads/row (16 ch each, 2x16B loads/edge).
// NOTE: r8 (thread reshape), r11 (parity split), r12 (pairwise unroll) all regressed
// vs this exact loop body — do not reshape the gather.
// Also writes this slice's cnt cols into aout (replaces the standalone cnt kernel).
template<int NET>
__global__ __launch_bounds__(256) void msg_kernel(
    const uint* __restrict__ hb,           // [N][64] uints (h bf16 packed)
    const int* __restrict__ indptr,        // [N*NET+1] slice (absolute into elist)
    const int* __restrict__ elist,
    const ushort* __restrict__ Bfrag,      // fragment-ordered weights
    ushort* __restrict__ aout)             // target ah buffer; write cols 0..127 + cnt
{
    __shared__ ushort As[4][32][40];       // 10.25 KB, chunk-major, 80B rows
    const int tid = threadIdx.x;
    const int bm = blockIdx.x * 32;
    const int wave = tid >> 6, lane = tid & 63;
    const int quad = lane >> 4, lrow = lane & 15;
    const int wr = wave & 1, wc = wave >> 1;
    const int r = tid >> 3;                // node row 0..31
    const int oct = tid & 7;               // 16-ch group
    const int v = bm + r;

    uint* AsU = (uint*)As;                 // [ch][r][20] uints

    // cnt cols for this slice (deg per etype; zeros beyond NET)
    {
        const int bk = v * NET;
#pragma unroll
        for (int jj = 0; jj < 4; jj++) {
            int col = oct * 4 + jj;
            float cv = 0.f;
            if (col < NET) cv = (float)(indptr[bk + col + 1] - indptr[bk + col]);
            aout[(size_t)v * AH_S + 256 + col] = f2bu(cv);
        }
    }

    float4v acc[4] = {};

    for (int et = 0; et < NET; et++) {
        const int beg = indptr[v * NET + et], end = indptr[v * NET + et + 1];
        float av[16];
#pragma unroll
        for (int i = 0; i < 16; i++) av[i] = 0.f;

        for (int j = beg; j < end; j++) {
            int src = elist[j];
            const uint4* hp = (const uint4*)(hb + (size_t)src * 64 + oct * 8);
            uint4 u0 = hp[0];
            uint4 u1 = hp[1];
            av[0] += blo(u0.x); av[1] += bhi(u0.x);
            av[2] += blo(u0.y); av[3] += bhi(u0.y);
            av[4] += blo(u0.z); av[5] += bhi(u0.z);
            av[6] += blo(u0.w); av[7] += bhi(u0.w);
            av[8]  += blo(u1.x); av[9]  += bhi(u1.x);
            av[10] += blo(u1.y); av[11] += bhi(u1.y);
            av[12] += blo(u1.z); av[13] += bhi(u1.z);
            av[14] += blo(u1.w); av[15] += bhi(u1.w);
        }

        __syncthreads();                   // previous etype's As reads complete
        {
            int base = ((oct >> 1) * 32 + r) * 20 + (oct & 1) * 8;
#pragma unroll
            for (int u = 0; u < 8; u++)
                AsU[base + u] = (uint)f2bu(av[2 * u]) | ((uint)f2bu(av[2 * u + 1]) << 16);
        }
        __syncthreads();

#pragma unroll
        for (int ch = 0; ch < 4; ch++) {
            short8 af = *(const short8*)&As[ch][wr * 16 + lrow][quad * 8];
            const ushort* bp = Bfrag + ((size_t)(((et * 4 + ch) * 2 + wc) * 4) << 9) + lane * 8;
#pragma unroll
            for (int j2 = 0; j2 < 4; j2++) {
                short8 bfr = *(const short8*)(bp + j2 * 512);
                acc[j2] = __builtin_amdgcn_mfma_f32_16x16x32_bf16(af, bfr, acc[j2], 0, 0, 0);
            }
        }
    }

#pragma unroll
    for (int j2 = 0; j2 < 4; j2++) {
        int col = wc * 64 + j2 * 16 + lrow;
#pragma unroll
        for (int rr = 0; rr < 4; rr++) {
            size_t row = (size_t)(bm + wr * 16 + quad * 4 + rr);
            aout[row * AH_S + col] = f2bu(acc[j2][rr]);
        }
    }
}

// ================= GRU GEMM with fused gate epilogue (ping-pong, race-free) ============
__global__ __launch_bounds__(256) void gru_gemm_kernel(
    const ushort* __restrict__ A,          // ahIn base, lda AH_S
    const ushort* __restrict__ Bt,         // gruB [512][288] permuted
    const float* __restrict__ bias,        // [512] permuted
    ushort* __restrict__ ahOut, ushort* __restrict__ hbS)
{
    __shared__ ushort As[128 * 32];
    __shared__ ushort Bs[128 * 32];
    const int tid = threadIdx.x;
    const int bm = blockIdx.x * 128;
    const int bn = blockIdx.y * 128;
    const int wave = tid >> 6, lane = tid & 63;
    const int quad = lane >> 4, lrow = lane & 15;
    const int wr = wave & 1, wc = wave >> 1;

    float4v acc[4][4] = {};

    for (int k0 = 0; k0 < 288; k0 += 32) {
        __syncthreads();
#pragma unroll
        for (int p = 0; p < 2; p++) {
            int lin = p * 256 + tid;
            int r = lin >> 2;
            int kc = (lin & 3) * 8;
            int wb = (p * 256 + wave * 64) * 8;       // wave-uniform LDS base (ushorts)
            gld_lds16(A + (size_t)(bm + r) * AH_S + k0 + kc, &As[wb]);
            gld_lds16(Bt + (size_t)(bn + r) * 288 + k0 + kc, &Bs[wb]);
        }
        __syncthreads();
        short8 af[4], bfr[4];
#pragma unroll
        for (int i = 0; i < 4; i++)
            af[i] = *(const short8*)&As[(wr * 64 + i * 16 + lrow) * 32 + quad * 8];
#pragma unroll
        for (int j = 0; j < 4; j++)
            bfr[j] = *(const short8*)&Bs[(wc * 64 + j * 16 + lrow) * 32 + quad * 8];
#pragma unroll
        for (int i = 0; i < 4; i++)
#pragma unroll
            for (int j = 0; j < 4; j++)
                acc[i][j] = __builtin_amdgcn_mfma_f32_16x16x32_bf16(af[i], bfr[j], acc[i][j], 0, 0, 0);
    }

    const int ch = (bn >> 7) * 32 + wc * 16 + lrow;
    const float b0 = bias[bn + wc * 64 + lrow];
    const float b1 = bias[bn + wc * 64 + 16 + lrow];
    const float b2 = bias[bn + wc * 64 + 32 + lrow];
    const float b3 = bias[bn + wc * 64 + 48 + lrow];
#pragma unroll
    for (int i = 0; i < 4; i++) {
#pragma unroll
        for (int r = 0; r < 4; r++) {
            size_t row = (size_t)(bm + wr * 64 + i * 16 + quad * 4 + r);
            float rr = sigmoidf_(acc[i][0][r] + b0);
            float zz = sigmoidf_(acc[i][1][r] + b1);
            float nn = tanhf(acc[i][2][r] + b2 + rr * (acc[i][3][r] + b3));
            float hold = __uint_as_float(((uint)A[row * AH_S + 128 + ch]) << 16);
            float hnew = (1.f - zz) * nn + zz * hold;
            ushort hu = f2bu(hnew);
            ahOut[row * AH_S + 128 + ch] = hu;
            hbS[row * 128 + ch] = hu;
        }
    }
}

// ================= readout GEMM with fused sigmoid-mul epilogue =================
// Stage-1 mode (ahx != null): write o into ahx (the OTHER ping-pong buffer — never
// read by this kernel, so race-free): h-cols + feat-cols, plus hb.
// Stage-2 mode (rb != null): write bf16 rout only.
__global__ __launch_bounds__(256) void ro_gemm_kernel(
    const ushort* __restrict__ A,
    const ushort* __restrict__ Bt,         // [256][288]
    const float* __restrict__ bias,        // [256] permuted
    ushort* __restrict__ rb,
    ushort* __restrict__ ahx, ushort* __restrict__ hbS)
{
    __shared__ ushort As[128 * 32];
    __shared__ ushort Bs[128 * 32];
    const int tid = threadIdx.x;
    const int bm = blockIdx.x * 128;
    const int bn = blockIdx.y * 128;
    const int wave = tid >> 6, lane = tid & 63;
    const int quad = lane >> 4, lrow = lane & 15;
    const int wr = wave & 1, wc = wave >> 1;

    float4v acc[4][4] = {};

    for (int k0 = 0; k0 < 288; k0 += 32) {
        __syncthreads();
#pragma unroll
        for (int p = 0; p < 2; p++) {
            int lin = p * 256 + tid;
            int r = lin >> 2;
            int kc = (lin & 3) * 8;
            int wb = (p * 256 + wave * 64) * 8;
            gld_lds16(A + (size_t)(bm + r) * AH_S + k0 + kc, &As[wb]);
            gld_lds16(Bt + (size_t)(bn + r) * 288 + k0 + kc, &Bs[wb]);
        }
        __syncthreads();
        short8 af[4], bfr[4];
#pragma unroll
        for (int i = 0; i < 4; i++)
            af[i] = *(const short8*)&As[(wr * 64 + i * 16 + lrow) * 32 + quad * 8];
#pragma unroll
        for (int j = 0; j < 4; j++)
            bfr[j] = *(const short8*)&Bs[(wc * 64 + j * 16 + lrow) * 32 + quad * 8];
#pragma unroll
        for (int i = 0; i < 4; i++)
#pragma unroll
            for (int j = 0; j < 4; j++)
                acc[i][j] = __builtin_amdgcn_mfma_f32_16x16x32_bf16(af[i], bfr[j], acc[i][j], 0, 0, 0);
    }

    const int c0 = (bn >> 7) * 64 + wc * 32 + lrow;
    const int c1 = c0 + 16;
    const float bu0 = bias[bn + wc * 64 + lrow];
    const float bv0 = bias[bn + wc * 64 + 16 + lrow];
    const float bu1 = bias[bn + wc * 64 + 32 + lrow];
    const float bv1 = bias[bn + wc * 64 + 48 + lrow];
#pragma unroll
    for (int i = 0; i < 4; i++) {
#pragma unroll
        for (int r = 0; r < 4; r++) {
            size_t row = (size_t)(bm + wr * 64 + i * 16 + quad * 4 + r);
            float o0 = sigmoidf_(acc[i][0][r] + bu0) * (acc[i][1][r] + bv0);
            float o1 = sigmoidf_(acc[i][2][r] + bu1) * (acc[i][3][r] + bv1);
            ushort u0 = f2bu(o0), u1 = f2bu(o1);
            if (rb) {
                rb[row * 128 + c0] = u0;
                rb[row * 128 + c1] = u1;
            }
            if (ahx) {
                ahx[row * AH_S + 128 + c0] = u0;   // stage-2 h init
                ahx[row * AH_S + 128 + c1] = u1;
                ahx[row * AH_S + 288 + c0] = u0;   // stage-2 feat cols
                ahx[row * AH_S + 288 + c1] = u1;
                hbS[row * 128 + c0] = u0;
                hbS[row * 128 + c1] = u1;
            }
        }
    }
}

// ================= small fp32 GEMM (stage-3 x1) =================
__global__ __launch_bounds__(256) void gemm_kernel(
    const float* __restrict__ A, int lda,
    const float* __restrict__ B, int ldb,
    const float* __restrict__ bias,
    float* __restrict__ C, int ldc,
    int K, int act)
{
    __shared__ float As[32][68];
    __shared__ float Bs[32][68];
    const int tid = threadIdx.x;
    const int bm = blockIdx.x * 64;
    const int bn = blockIdx.y * 64;
    const int tm = (tid & 15) * 4;
    const int tn = (tid >> 4) * 4;
    float acc[4][4] = {};

    for (int k0 = 0; k0 < K; k0 += 32) {
#pragma unroll
        for (int p = 0; p < 2; p++) {
            int lin = p * 256 + tid;
            int ar = lin >> 3;
            int ac = (lin & 7) << 2;
            float4 av = *(const float4*)(A + (size_t)(bm + ar) * lda + (k0 + ac));
            As[ac + 0][ar] = av.x;
            As[ac + 1][ar] = av.y;
            As[ac + 2][ar] = av.z;
            As[ac + 3][ar] = av.w;
            int br = lin >> 4;
            int bc = (lin & 15) << 2;
            *(float4*)&Bs[br][bc] = *(const float4*)(B + (size_t)(k0 + br) * ldb + (bn + bc));
        }
        __syncthreads();
#pragma unroll
        for (int k = 0; k < 32; k++) {
            float4 a4 = *(const float4*)&As[k][tm];
            float4 b4 = *(const float4*)&Bs[k][tn];
            float av[4] = {a4.x, a4.y, a4.z, a4.w};
            float bv[4] = {b4.x, b4.y, b4.z, b4.w};
#pragma unroll
            for (int i = 0; i < 4; i++)
#pragma unroll
                for (int j = 0; j < 4; j++)
                    acc[i][j] += av[i] * bv[j];
        }
        __syncthreads();
    }
#pragma unroll
    for (int i = 0; i < 4; i++) {
        size_t row = (size_t)(bm + tm + i);
#pragma unroll
        for (int j = 0; j < 4; j++) {
            int col = bn + tn + j;
            float val = acc[i][j] + (bias ? bias[col] : 0.f);
            if (act == 1) val = fmaxf(val, 0.f);
            C[row * ldc + col] = val;
        }
    }
}

// ================= fused x2 GEMM + output dot (64 blocks, parallel) =================
// Block = one output row; 128 threads: t computes x2[row][t] (K=256 from LDS-staged
// x1 row), relu, multiply by wo[t]; 2-wave reduction -> out[row].
__global__ __launch_bounds__(128) void mlp_tail_kernel(
    const float* __restrict__ x1, const float* __restrict__ w1,
    const float* __restrict__ b1, const float* __restrict__ wo,
    const float* __restrict__ bo, float* __restrict__ out)
{
    __shared__ float xs[256];
    __shared__ float part[2];
    int row = blockIdx.x;
    int t = threadIdx.x;
    xs[t] = x1[row * 256 + t];
    xs[t + 128] = x1[row * 256 + t + 128];
    __syncthreads();
    float acc = 0.f;
    for (int k = 0; k < 256; k++) acc += xs[k] * w1[k * 128 + t];
    float s = fmaxf(acc + b1[t], 0.f) * wo[t];
#pragma unroll
    for (int off = 32; off; off >>= 1) s += __shfl_down(s, off);
    if ((t & 63) == 0) part[t >> 6] = s;
    __syncthreads();
    if (t == 0) out[row] = part[0] + part[1] + bo[0];
}

// ================= fused weight prep (both stages + cursor zeroing, one dispatch) =====
__device__ __forceinline__ void prep_bfrag_item(const float* W, ushort* Bf, int idx)
{
    int m = idx & 7;
    int lane = (idx >> 3) & 63;
    int f = idx >> 9;
    int j = f & 3; f >>= 2;
    int wc = f & 1; f >>= 1;
    int ch = f & 3;
    int et = f >> 2;
    int quad = lane >> 4, lrow = lane & 15;
    int k = ch * 32 + quad * 8 + m;
    int c = wc * 64 + j * 16 + lrow;
    Bf[idx] = f2bu(W[et * 16384 + k * 128 + c]);
}

__device__ __forceinline__ void prep_gru_item(const float* wih, const float* whh,
                                              const float* bih, const float* bhh,
                                              const float* b, int net,
                                              ushort* Bt, float* bias, int idx)
{
    int p = idx / 288;
    int k = idx - p * 288;
    int g = (p >> 4) & 3;
    int c = (p >> 7) * 32 + ((p >> 6) & 1) * 16 + (p & 15);
    float val = 0.f;
    if (k < 128) {
        if (g == 0)      val = wih[k * 384 + c];
        else if (g == 1) val = wih[k * 384 + 128 + c];
        else if (g == 2) val = wih[k * 384 + 256 + c];
    } else if (k < 256) {
        int kk = k - 128;
        if (g == 0)      val = whh[kk * 384 + c];
        else if (g == 1) val = whh[kk * 384 + 128 + c];
        else if (g == 3) val = whh[kk * 384 + 256 + c];
    } else {
        int j = k - 256;
        if (j < net && g < 3) {
            int col = g * 128 + c;
            float s = 0.f;
            for (int kk = 0; kk < 128; kk++) s += b[j * 128 + kk] * wih[kk * 384 + col];
            val = s;
        }
    }
    Bt[idx] = f2bu(val);
    if (k == 0) {
        float bv;
        if (g == 0)      bv = bih[c] + bhh[c];
        else if (g == 1) bv = bih[128 + c] + bhh[128 + c];
        else if (g == 2) bv = bih[256 + c];
        else             bv = bhh[256 + c];
        bias[p] = bv;
    }
}

__device__ __forceinline__ void prep_ro_item(const float* iw, const float* jw,
                                             const float* ib, const float* jb,
                                             int Fin, ushort* Bt, float* bias, int idx)
{
    int p = idx / 288;
    int k = idx - p * 288;
    int j = (p >> 4) & 3;
    int s = j & 1;
    int c = ((p >> 7) & 1) * 64 + ((p >> 6) & 1) * 32 + (j >> 1) * 16 + (p & 15);
    float val = 0.f;
    if (k < 128) {
        val = s ? jw[k * 128 + c] : iw[k * 128 + c];
    } else if (k >= 160) {
        int kf = k - 160;
        if (kf < Fin && s == 0) val = iw[(128 + kf) * 128 + c];
    }
    Bt[idx] = f2bu(val);
    if (k == 0) bias[p] = s ? jb[c] : ib[c];
}

// prep sections: bf1 81920 | gru1 147456 | ro1 73728 | bf2 147456 | gru2 147456 | ro2 73728
// plus cursor[0..KN_TOT) zeroing. Grid covers max(671744, KN_TOT)=702464 -> 2744 blocks.
__global__ __launch_bounds__(256) void prep_all_kernel(
    const float* W1, const float* b1, const float* wih1, const float* whh1,
    const float* bih1, const float* bhh1, const float* iw1, const float* ib1,
    const float* jw1, const float* jb1,
    const float* W2, const float* b2, const float* wih2, const float* whh2,
    const float* bih2, const float* bhh2, const float* iw2, const float* ib2,
    const float* jw2, const float* jb2,
    ushort* bf1, ushort* gru1, float* gb1, ushort* ro1, float* rb1,
    ushort* bf2, ushort* gru2, float* gb2, ushort* ro2, float* rb2,
    int* cursor)
{
    int gid = blockIdx.x * 256 + threadIdx.x;
    if (gid < KN_TOT) cursor[gid] = 0;
    if (gid < 81920)            prep_bfrag_item(W1, bf1, gid);
    else if (gid < 229376)      prep_gru_item(wih1, whh1, bih1, bhh1, b1, 5, gru1, gb1, gid - 81920);
    else if (gid < 303104)      prep_ro_item(iw1, jw1, ib1, jb1, 64, ro1, rb1, gid - 229376);
    else if (gid < 450560)      prep_bfrag_item(W2, bf2, gid - 303104);
    else if (gid < 598016)      prep_gru_item(wih2, whh2, bih2, bhh2, b2, 9, gru2, gb2, gid - 450560);
    else if (gid < 671744)      prep_ro_item(iw2, jw2, ib2, jb2, 128, ro2, rb2, gid - 598016);
}

// ================= merged CSR build =================
__global__ void hist2_kernel(const int* __restrict__ bd, const int* __restrict__ be,
                             const int* __restrict__ kd, const int* __restrict__ ke,
                             int* __restrict__ counts)
{
    int e = blockIdx.x * blockDim.x + threadIdx.x;
    if (e >= E_TOT) return;
    if (e < E_BI) atomicAdd(&counts[bd[e] * 5 + be[e]], 1);
    else { int i = e - E_BI; atomicAdd(&counts[KN_BI + kd[i] * 9 + ke[i]], 1); }
}

__global__ void scan1_kernel(const int* __restrict__ counts, int* __restrict__ local_ex,
                             int* __restrict__ partial)
{
    __shared__ int s[256];
    int t = threadIdx.x;
    int i = blockIdx.x * 256 + t;
    int v = counts[i];
    s[t] = v;
    __syncthreads();
    for (int off = 1; off < 256; off <<= 1) {
        int x = 0;
        if (t >= off) x = s[t - off];
        __syncthreads();
        if (t >= off) s[t] += x;
        __syncthreads();
    }
    local_ex[i] = s[t] - v;
    if (t == 255) partial[blockIdx.x] = s[255];
}

__global__ void scan2b_kernel(int* __restrict__ partial, int nb, int* __restrict__ last, int E)
{
    __shared__ int s[256];
    int t = threadIdx.x;
    int loc[11];
    int sum = 0;
#pragma unroll
    for (int q = 0; q < 11; q++) {
        int idx = t * 11 + q;
        int v = (idx < nb) ? partial[idx] : 0;
        loc[q] = sum; sum += v;
    }
    s[t] = sum;
    __syncthreads();
    for (int off = 1; off < 256; off <<= 1) {
        int x = 0;
        if (t >= off) x = s[t - off];
        __syncthreads();
        if (t >= off) s[t] += x;
        __syncthreads();
    }
    int excl = s[t] - sum;
#pragma unroll
    for (int q = 0; q < 11; q++) {
        int idx = t * 11 + q;
        if (idx < nb) partial[idx] = excl + loc[q];
    }
    if (t == 0) *last = E;
}

__global__ void scan3c_kernel(int* __restrict__ indptr, const int* __restrict__ partial,
                              int* __restrict__ cursor)
{
    int i = blockIdx.x * 256 + threadIdx.x;
    int v = indptr[i] + partial[blockIdx.x];
    indptr[i] = v;
    cursor[i] = v;
}

__global__ void fill2_kernel(const int* __restrict__ bs, const int* __restrict__ bd,
                             const int* __restrict__ be,
                             const int* __restrict__ ks, const int* __restrict__ kd,
                             const int* __restrict__ ke,
                             int* __restrict__ cursor, int* __restrict__ elist)
{
    int e = blockIdx.x * blockDim.x + threadIdx.x;
    if (e >= E_TOT) return;
    if (e < E_BI) {
        int pos = atomicAdd(&cursor[bd[e] * 5 + be[e]], 1);
        elist[pos] = bs[e];
    } else {
        int i = e - E_BI;
        int pos = atomicAdd(&cursor[KN_BI + kd[i] * 9 + ke[i]], 1);
        elist[pos] = ks[i];
    }
}

// ================= elementwise =================
// stage-1 pad: feat fp32 -> ahA h-cols + feat cols (both) + hb + cnt cols (ahA)
__global__ void pad_cnt_kernel(const float* __restrict__ fsrc,
                               const int* __restrict__ indptr, int net,
                               uint* __restrict__ ahA, uint* __restrict__ ahB,
                               uint* __restrict__ hb, int Fin)
{
    int idx = blockIdx.x * blockDim.x + threadIdx.x;   // N*32
    int v = idx >> 5;
    int j = idx & 31;
    int c = j * 4;
    float4 val = make_float4(0.f, 0.f, 0.f, 0.f);
    if (c < Fin) val = *(const float4*)(fsrc + (size_t)v * Fin + c);
    uint2 pk;
    pk.x = (uint)f2bu(val.x) | ((uint)f2bu(val.y) << 16);
    pk.y = (uint)f2bu(val.z) | ((uint)f2bu(val.w) << 16);
    *(uint2*)(ahA + (size_t)v * AH_U + 64 + c / 2) = pk;    // h cols (step-0 input)
    *(uint2*)(ahA + (size_t)v * AH_U + 144 + c / 2) = pk;   // feat cols
    *(uint2*)(ahB + (size_t)v * AH_U + 144 + c / 2) = pk;
    *(uint2*)(hb + (size_t)v * 64 + c / 2) = pk;
    float cv = 0.f;
    if (j < net) cv = (float)(indptr[v * net + j + 1] - indptr[v * net + j]);
    ((ushort*)ahA)[(size_t)v * AH_S + 256 + j] = f2bu(cv);
}

// pool from bf16 readout
__global__ void pool_kernel(const ushort* __restrict__ r2, float* __restrict__ pooled)
{
    int s = blockIdx.x;
    int c = threadIdx.x;
    const ushort* base = r2 + (size_t)(2 * s) * PER * 128;
    float acc = 0.f;
    for (int i = 0; i < PER; i++)
        acc += __uint_as_float(((uint)base[(size_t)i * 128 + c]) << 16);
    pooled[s * 128 + c] = acc;
}

struct GGParams {
    const float *W, *b, *wih, *whh, *bih, *bhh, *iw, *ib, *jw, *jb;
};

extern "C" void kernel_launch(void* const* d_in, const int* in_sizes, int n_in,
                              void* d_out, int out_size, void* d_ws, size_t ws_size,
                              hipStream_t stream)
{
    const float* feat    = (const float*)d_in[0];
    const int*   bi_src  = (const int*)d_in[1];
    const int*   bi_dst  = (const int*)d_in[2];
    const int*   bi_et   = (const int*)d_in[3];
    const int*   knn_src = (const int*)d_in[4];
    const int*   knn_dst = (const int*)d_in[5];
    const int*   knn_et  = (const int*)d_in[6];

    GGParams s1 { (const float*)d_in[8],  (const float*)d_in[9],  (const float*)d_in[10],
                  (const float*)d_in[11], (const float*)d_in[12], (const float*)d_in[13],
                  (const float*)d_in[14], (const float*)d_in[15], (const float*)d_in[16],
                  (const float*)d_in[17] };
    GGParams s2 { (const float*)d_in[18], (const float*)d_in[19], (const float*)d_in[20],
                  (const float*)d_in[21], (const float*)d_in[22], (const float*)d_in[23],
                  (const float*)d_in[24], (const float*)d_in[25], (const float*)d_in[26],
                  (const float*)d_in[27] };
    const float* w0 = (const float*)d_in[28];
    const float* b0 = (const float*)d_in[29];
    const float* w1 = (const float*)d_in[30];
    const float* b1 = (const float*)d_in[31];
    const float* wo = (const float*)d_in[32];
    const float* bo = (const float*)d_in[33];

    const int N = N_NODES;
    const size_t n128 = (size_t)N * 128;

    float* ws = (float*)d_ws;
    size_t off = 0;
    __hip_bfloat16* ah0 = (__hip_bfloat16*)(ws + off);  off += (size_t)N * 208;
    __hip_bfloat16* ah1 = (__hip_bfloat16*)(ws + off);  off += (size_t)N * 208;
    float* G = ws + off;                                off += 2 * n128;
    uint* hb = (uint*)(G + n128);                       // second half of G
    ushort* bfragB1 = (ushort*)(ws + off);              off += 81920 / 2;
    ushort* bfragB2 = (ushort*)(ws + off);              off += 147456 / 2;
    ushort* gruB1 = (ushort*)(ws + off);                off += 147456 / 2;
    ushort* gruB2 = (ushort*)(ws + off);                off += 147456 / 2;
    ushort* roB1 = (ushort*)(ws + off);                 off += 73728 / 2;
    ushort* roB2 = (ushort*)(ws + off);                 off += 73728 / 2;
    float* gruBias1 = ws + off;                         off += 512;
    float* gruBias2 = ws + off;                         off += 512;
    float* roBias1 = ws + off;                          off += 256;
    float* roBias2 = ws + off;                          off += 256;
    int* indptr  = (int*)(ws + off);                    off += KN_TOT + 8;
    int* cursor  = (int*)(ws + off);                    off += KN_TOT;
    int* partial = (int*)(ws + off);                    off += 4096;
    int* elist   = (int*)(ws + off);                    off += E_TOT;
    float* pooled = ws + off;                           off += 64 * 128;
    float* x1 = ws + off;                               off += 64 * 256;

    ushort* ahA = (ushort*)ah0;
    ushort* ahB = (ushort*)ah1;
    ushort* hbS = (ushort*)hb;

    // ---- fused weight prep + cursor zeroing (1 dispatch) ----
    prep_all_kernel<<<2744, 256, 0, stream>>>(
        s1.W, s1.b, s1.wih, s1.whh, s1.bih, s1.bhh, s1.iw, s1.ib, s1.jw, s1.jb,
        s2.W, s2.b, s2.wih, s2.whh, s2.bih, s2.bhh, s2.iw, s2.ib, s2.jw, s2.jb,
        bfragB1, gruB1, gruBias1, roB1, roBias1,
        bfragB2, gruB2, gruBias2, roB2, roBias2,
        cursor);

    // ---- merged CSR build ----
    hist2_kernel<<<(E_TOT + 255) / 256, 256, 0, stream>>>(bi_dst, bi_et, knn_dst, knn_et, cursor);
    scan1_kernel<<<KN_TOT / 256, 256, 0, stream>>>(cursor, indptr, partial);
    scan2b_kernel<<<1, 256, 0, stream>>>(partial, KN_TOT / 256, indptr + KN_TOT, E_TOT);
    scan3c_kernel<<<KN_TOT / 256, 256, 0, stream>>>(indptr, partial, cursor);
    fill2_kernel<<<(E_TOT + 255) / 256, 256, 0, stream>>>(bi_src, bi_dst, bi_et,
                                                          knn_src, knn_dst, knn_et,
                                                          cursor, elist);

    // ================= Stage 1: bond graph (5 etypes), Fin=64 =================
    pad_cnt_kernel<<<(N * 32) / 256, 256, 0, stream>>>(feat, indptr, 5,
                                                       (uint*)ahA, (uint*)ahB, hb, 64);
    {
        ushort* ahIn = ahA;
        ushort* ahOut = ahB;
        for (int step = 0; step < 2; step++) {
            msg_kernel<5><<<N / 32, 256, 0, stream>>>(hb, indptr, elist, bfragB1, ahIn);
            dim3 g(N / 128, 4);
            gru_gemm_kernel<<<g, 256, 0, stream>>>(ahIn, gruB1, gruBias1, ahOut, hbS);
            ushort* t = ahIn; ahIn = ahOut; ahOut = t;
        }
        // ahIn == ahA here; stage-1 readout reads ahA, writes stage-2 operands into ahB
        dim3 gr(N / 128, 2);
        ro_gemm_kernel<<<gr, 256, 0, stream>>>(ahIn + 128, roB1, roBias1,
                                               nullptr, ahB, hbS);
    }

    // ================= Stage 2: knn graph (9 etypes), ping-pong starts at ahB ==========
    // (cnt cols written by each msg dispatch into its target buffer)
    __hip_bfloat16* r2b = (__hip_bfloat16*)G;   // first half of G
    {
        ushort* ahIn = ahB;
        ushort* ahOut = ahA;
        for (int step = 0; step < 2; step++) {
            msg_kernel<9><<<N / 32, 256, 0, stream>>>(hb, indptr + KN_BI, elist, bfragB2, ahIn);
            dim3 g(N / 128, 4);
            gru_gemm_kernel<<<g, 256, 0, stream>>>(ahIn, gruB2, gruBias2, ahOut, hbS);
            ushort* t = ahIn; ahIn = ahOut; ahOut = t;
        }
        // ahIn == ahB here: h (latest), cnt (msg step-1 wrote... step-0 wrote ahB), feat
        dim3 gr(N / 128, 2);
        ro_gemm_kernel<<<gr, 256, 0, stream>>>(ahIn + 128, roB2, roBias2,
                                               (ushort*)r2b, nullptr, nullptr);
    }

    // ================= Stage 3: ligand pooling + MLP =================
    pool_kernel<<<64, 128, 0, stream>>>((const ushort*)r2b, pooled);
    {
        dim3 g1(1, 4);
        gemm_kernel<<<g1, 256, 0, stream>>>(pooled, 128, w0, 256, b0, x1, 256, 128, 1);
    }
    mlp_tail_kernel<<<64, 128, 0, stream>>>(x1, w1, b1, wo, bo, (float*)d_out);
}